// Round 1
// baseline (179.302 us; speedup 1.0000x reference)
//
#include <hip/hip_runtime.h>
#include <math.h>

// TripleAttention: B=1, N=384, C=D=64, H=1.
// out[i,d] = num/den with
//   num[i,d] = sum_{j,k} R[i,j] P[i,k] Q[j,k] v1[j,d] v2[k,d]
//   den[i]   = sum_{j,k} R[i,j] P[i,k] Q[j,k]
// R=exp(AB-mAB), P=exp(CD-mCD), Q=exp(EF-mEF); max shift cancels in the ratio.

#define NN 384
#define DD 64
#define NO 512

__device__ __forceinline__ unsigned encf(float f) {
    int i = __float_as_int(f);
    return (i >= 0) ? ((unsigned)i ^ 0x80000000u) : ~(unsigned)i;
}
__device__ __forceinline__ float decf(unsigned u) {
    return (u & 0x80000000u) ? __int_as_float((int)(u ^ 0x80000000u))
                             : __int_as_float((int)~u);
}

// ---------------- kernel 1: proj = x @ W^T  [384,512] ----------------
__global__ void proj_kernel(const float* __restrict__ x, const float* __restrict__ W,
                            float* __restrict__ proj) {
    int n = blockIdx.x;
    __shared__ float xs[64];
    if (threadIdx.x < 64) xs[threadIdx.x] = x[n * 64 + threadIdx.x];
    __syncthreads();
    const float4* xv4 = (const float4*)xs;
    for (int r = 0; r < 2; ++r) {
        int o = threadIdx.x + r * 256;
        const float4* w4 = (const float4*)(W + o * 64);
        float s = 0.f;
#pragma unroll
        for (int c = 0; c < 16; ++c) {
            float4 wv = w4[c];
            float4 xv = xv4[c];
            s += wv.x * xv.x + wv.y * xv.y + wv.z * xv.z + wv.w * xv.w;
        }
        proj[n * 512 + o] = s;
    }
}

// ---------------- kernel 2: AB, CD, EFt scores + per-matrix max ----------------
// m=0: AB[i,j]= a.b/8   (a=col0,  b=col64)
// m=1: CD[i,k]= c.d/8   (c=col128,d=col192)
// m=2: EFt[k,j]= e.f/8 transposed: rows use f(col320), cols use e(col256)
__global__ void scores_kernel(const float* __restrict__ proj,
                              float* __restrict__ AB, float* __restrict__ CDm,
                              float* __restrict__ EFt, unsigned* __restrict__ mx) {
    int m = blockIdx.z;
    int bi = blockIdx.y, bj = blockIdx.x;
    int tid = threadIdx.x;
    int tx = tid % 16, ty = tid / 16;
    int aoff, boff;
    float* out;
    if (m == 0)      { aoff = 0;   boff = 64;  out = AB;  }
    else if (m == 1) { aoff = 128; boff = 192; out = CDm; }
    else             { aoff = 320; boff = 256; out = EFt; }

    __shared__ float As[32][65], Bs[32][65];
    for (int r = 0; r < 8; ++r) {
        int idx = tid + r * 256;          // 0..2047
        int row = idx / 64, col = idx % 64;
        As[row][col] = proj[(bi * 32 + row) * 512 + aoff + col];
        Bs[row][col] = proj[(bj * 32 + row) * 512 + boff + col];
    }
    __syncthreads();

    float acc[2][2] = {{0.f, 0.f}, {0.f, 0.f}};
#pragma unroll 8
    for (int d = 0; d < 64; ++d) {
        float a0 = As[ty * 2][d], a1 = As[ty * 2 + 1][d];
        float b0 = Bs[tx * 2][d], b1 = Bs[tx * 2 + 1][d];
        acc[0][0] += a0 * b0; acc[0][1] += a0 * b1;
        acc[1][0] += a1 * b0; acc[1][1] += a1 * b1;
    }
    float mymax = -3.0e38f;
#pragma unroll
    for (int a = 0; a < 2; ++a)
#pragma unroll
        for (int b = 0; b < 2; ++b) {
            float v = acc[a][b] * 0.125f;
            out[(bi * 32 + ty * 2 + a) * NN + bj * 32 + tx * 2 + b] = v;
            mymax = fmaxf(mymax, v);
        }
    __shared__ float red[256];
    red[tid] = mymax;
    __syncthreads();
    for (int s = 128; s > 0; s >>= 1) {
        if (tid < s) red[tid] = fmaxf(red[tid], red[tid + s]);
        __syncthreads();
    }
    if (tid == 0) atomicMax(&mx[m], encf(red[0]));
}

// ---------------- kernel 3: in-place exp of the 3 matrices ----------------
__global__ void exp3_kernel(float* __restrict__ AB, float* __restrict__ CDm,
                            float* __restrict__ EFt, const unsigned* __restrict__ mx) {
    int b = blockIdx.x;              // 432 blocks, 144 per matrix (1024 elems each)
    int m = b / 144;
    float mval = decf(mx[m]);
    float* ptr = (m == 0) ? AB : (m == 1) ? CDm : EFt;
    int idx = (b % 144) * 1024 + threadIdx.x * 4;
    float4 v = *(float4*)(ptr + idx);
    v.x = expf(v.x - mval); v.y = expf(v.y - mval);
    v.z = expf(v.z - mval); v.w = expf(v.w - mval);
    *(float4*)(ptr + idx) = v;
}

// ---------------- kernel 4: den[i] = sum_j R[i,j] * (P @ Qt)[i,j] ----------------
__global__ void den_kernel(const float* __restrict__ R, const float* __restrict__ P,
                           const float* __restrict__ Qt, float* __restrict__ den) {
    int bi = blockIdx.y, bj = blockIdx.x;
    int tid = threadIdx.x;
    int tx = tid % 16, ty = tid / 16;
    __shared__ float Ps[32][33], Qs[32][33];
    float u[2][2] = {{0.f, 0.f}, {0.f, 0.f}};
    for (int k0 = 0; k0 < NN; k0 += 32) {
        for (int r = 0; r < 4; ++r) {
            int idx = tid + r * 256;       // 0..1023
            int row = idx / 32, col = idx % 32;
            Ps[row][col] = P[(bi * 32 + row) * NN + k0 + col];
            Qs[row][col] = Qt[(k0 + row) * NN + bj * 32 + col];
        }
        __syncthreads();
#pragma unroll 8
        for (int kk = 0; kk < 32; ++kk) {
            float p0 = Ps[ty * 2][kk], p1 = Ps[ty * 2 + 1][kk];
            float q0 = Qs[kk][tx * 2], q1 = Qs[kk][tx * 2 + 1];
            u[0][0] += p0 * q0; u[0][1] += p0 * q1;
            u[1][0] += p1 * q0; u[1][1] += p1 * q1;
        }
        __syncthreads();
    }
    int ib = bi * 32 + ty * 2, jb = bj * 32 + tx * 2;
    float p0 = u[0][0] * R[ib * NN + jb] + u[0][1] * R[ib * NN + jb + 1];
    float p1 = u[1][0] * R[(ib + 1) * NN + jb] + u[1][1] * R[(ib + 1) * NN + jb + 1];
    __shared__ float redr[32][16];
    redr[ty * 2][tx] = p0;
    redr[ty * 2 + 1][tx] = p1;
    __syncthreads();
    if (tid < 32) {
        float s = 0.f;
#pragma unroll
        for (int t = 0; t < 16; ++t) s += redr[tid][t];
        atomicAdd(&den[bi * 32 + tid], s);
    }
}

// ---------------- kernel 5: main contraction ----------------
// grid (384 i, 2 jh). Per block: T[j,d] = sum_k Qt[k,j]*pi[k]*v2[k,d] for 192 j,
// then num[i,d] += sum_j R[i,j]*v1[j,d]*T[j,d].
__global__ __launch_bounds__(256) void main_kernel(const float* __restrict__ R,
                                                   const float* __restrict__ P,
                                                   const float* __restrict__ Qt,
                                                   const float* __restrict__ proj,
                                                   float* __restrict__ num) {
    int i = blockIdx.x, jh = blockIdx.y;
    int tid = threadIdx.x;
    int tx = tid % 16, ty = tid / 16;

    __shared__ float pi_s[NN];
    __shared__ float4 qt4[32 * 48];     // Qt tile [32 k][192 j]
    __shared__ float4 v2s4[32 * 16];    // pi-scaled v2 tile [32 k][64 d]

    pi_s[tid] = P[i * NN + tid];
    if (tid < 128) pi_s[256 + tid] = P[i * NN + 256 + tid];

    float4 acc[12];
#pragma unroll
    for (int a = 0; a < 12; ++a) acc[a] = make_float4(0.f, 0.f, 0.f, 0.f);

    for (int k0 = 0; k0 < NN; k0 += 32) {
        __syncthreads();
#pragma unroll
        for (int r = 0; r < 6; ++r) {
            int f4 = tid + r * 256;          // 0..1535
            int k = f4 / 48, jf = f4 % 48;
            qt4[f4] = *(const float4*)(Qt + (k0 + k) * NN + jh * 192 + jf * 4);
        }
#pragma unroll
        for (int r = 0; r < 2; ++r) {
            int f4 = tid + r * 256;          // 0..511
            int k = f4 / 16, df = f4 % 16;
            float pk = pi_s[k0 + k];
            float4 v = *(const float4*)(proj + (k0 + k) * 512 + 448 + df * 4);
            v.x *= pk; v.y *= pk; v.z *= pk; v.w *= pk;
            v2s4[f4] = v;
        }
        __syncthreads();
#pragma unroll
        for (int kk = 0; kk < 32; ++kk) {
            float4 bv = v2s4[kk * 16 + tx];
            float4 a0 = qt4[kk * 48 + ty * 3 + 0];
            float4 a1 = qt4[kk * 48 + ty * 3 + 1];
            float4 a2 = qt4[kk * 48 + ty * 3 + 2];
#define FMA4(S, IDX)                                                     \
            { float s_ = (S);                                            \
              acc[IDX].x += s_ * bv.x; acc[IDX].y += s_ * bv.y;          \
              acc[IDX].z += s_ * bv.z; acc[IDX].w += s_ * bv.w; }
            FMA4(a0.x, 0) FMA4(a0.y, 1) FMA4(a0.z, 2) FMA4(a0.w, 3)
            FMA4(a1.x, 4) FMA4(a1.y, 5) FMA4(a1.z, 6) FMA4(a1.w, 7)
            FMA4(a2.x, 8) FMA4(a2.y, 9) FMA4(a2.z, 10) FMA4(a2.w, 11)
#undef FMA4
        }
    }

    // epilogue: pn[d] = sum over this thread's 12 j of R[i,j]*v1[j,d]*T[j,d]
    float4 pn = make_float4(0.f, 0.f, 0.f, 0.f);
#pragma unroll
    for (int jj = 0; jj < 12; ++jj) {
        int j = jh * 192 + ty * 12 + jj;
        float w = R[i * NN + j];
        float4 v1v = *(const float4*)(proj + j * 512 + 384 + tx * 4);
        pn.x += w * v1v.x * acc[jj].x;
        pn.y += w * v1v.y * acc[jj].y;
        pn.z += w * v1v.z * acc[jj].z;
        pn.w += w * v1v.w * acc[jj].w;
    }
    __syncthreads();
    float* red = (float*)qt4;            // reuse as [16][64]
    ((float4*)red)[ty * 16 + tx] = pn;
    __syncthreads();
    if (tid < 64) {
        float s = 0.f;
#pragma unroll
        for (int t = 0; t < 16; ++t) s += red[t * 64 + tid];
        atomicAdd(&num[i * 64 + tid], s);
    }
}

// ---------------- kernel 6: out = num / den ----------------
__global__ void finalize_kernel(const float* __restrict__ num, const float* __restrict__ den,
                                float* __restrict__ out) {
    int idx = blockIdx.x * 256 + threadIdx.x;   // 24576
    out[idx] = num[idx] / den[idx / 64];
}

extern "C" void kernel_launch(void* const* d_in, const int* in_sizes, int n_in,
                              void* d_out, int out_size, void* d_ws, size_t ws_size,
                              hipStream_t stream) {
    const float* x = (const float*)d_in[0];      // [1,384,64]
    const float* W = (const float*)d_in[1];      // [512,64]
    float* out = (float*)d_out;                  // [384,64]

    float* ws   = (float*)d_ws;                  // needs ~2.66 MB
    float* proj = ws;                            // 196608
    float* AB   = ws + 196608;                   // 147456 (-> R)
    float* CDm  = ws + 344064;                   // 147456 (-> P)
    float* EFt  = ws + 491520;                   // 147456 (-> Qt, k-major)
    float* num  = ws + 638976;                   // 24576
    float* den  = ws + 663552;                   // 384
    unsigned* mx = (unsigned*)(ws + 663936);     // 3

    // zero num, den, maxes (contiguous: 24576+384+3 = 24963 floats)
    hipMemsetAsync(num, 0, 24963 * sizeof(float), stream);

    proj_kernel<<<NN, 256, 0, stream>>>(x, W, proj);
    scores_kernel<<<dim3(12, 12, 3), 256, 0, stream>>>(proj, AB, CDm, EFt, mx);
    exp3_kernel<<<432, 256, 0, stream>>>(AB, CDm, EFt, mx);
    den_kernel<<<dim3(12, 12), 256, 0, stream>>>(AB, CDm, EFt, den);
    main_kernel<<<dim3(NN, 2), 256, 0, stream>>>(AB, CDm, EFt, proj, num);
    finalize_kernel<<<96, 256, 0, stream>>>(num, den, out);
}

// Round 2
// 137.222 us; speedup vs baseline: 1.3067x; 1.3067x over previous
//
#include <hip/hip_runtime.h>
#include <math.h>

// TripleAttention: B=1, N=384, C=D=64, H=1.
// out[i,d] = num/den with
//   num[i,d] = sum_{j,k} R[i,j] P[i,k] Q[j,k] v1[j,d] v2[k,d]
//   den[i]   = sum_{j,k} R[i,j] P[i,k] Q[j,k]
// R=exp(AB), P=exp(CD), Q=exp(EF); the reference's global-max shift cancels
// exactly in num/den (scores ~N(0,0.16) so unshifted exp is safe in fp32).
// Main contraction on MFMA bf16 with hi/lo split (3 products) for ~2^-16
// relative accuracy.

#define NN 384

using short8 = __attribute__((ext_vector_type(8))) short;
using f32x4  = __attribute__((ext_vector_type(4))) float;
typedef unsigned short u16;
typedef unsigned int u32;

// ---------------- kernel 1: proj = x @ W^T  [384,512]; also v1t/v2t transposes ----------------
__global__ void proj_kernel(const float* __restrict__ x, const float* __restrict__ W,
                            float* __restrict__ proj, float* __restrict__ v1t,
                            float* __restrict__ v2t) {
    int n = blockIdx.x;
    __shared__ float xs[64];
    if (threadIdx.x < 64) xs[threadIdx.x] = x[n * 64 + threadIdx.x];
    __syncthreads();
    const float4* xv4 = (const float4*)xs;
    for (int r = 0; r < 2; ++r) {
        int o = threadIdx.x + r * 256;
        const float4* w4 = (const float4*)(W + o * 64);
        float s = 0.f;
#pragma unroll
        for (int c = 0; c < 16; ++c) {
            float4 wv = w4[c];
            float4 xv = xv4[c];
            s += wv.x * xv.x + wv.y * xv.y + wv.z * xv.z + wv.w * xv.w;
        }
        proj[n * 512 + o] = s;
        if (o >= 448)      v2t[(o - 448) * NN + n] = s;   // v2 transposed [d][n]
        else if (o >= 384) v1t[(o - 384) * NN + n] = s;   // v1 transposed [d][n]
    }
}

// ---------------- kernel 2: scores + exp (+ bf16 split for Q) ----------------
// m=0: R[i,j] = exp(a.b/8)   (a=col0,   b=col64)
// m=1: P[i,k] = exp(c.d/8)   (c=col128, d=col192)
// m=2: Q[j,k] = exp(e.f/8)   (e=col256, f=col320) -> Qhi/Qlo bf16 split
__global__ void scores_exp_kernel(const float* __restrict__ proj,
                                  float* __restrict__ R, float* __restrict__ P,
                                  u16* __restrict__ Qhi, u16* __restrict__ Qlo) {
    int m = blockIdx.z;
    int bi = blockIdx.y, bj = blockIdx.x;
    int tid = threadIdx.x;
    int tx = tid % 16, ty = tid / 16;
    int aoff, boff;
    if (m == 0)      { aoff = 0;   boff = 64;  }
    else if (m == 1) { aoff = 128; boff = 192; }
    else             { aoff = 256; boff = 320; }

    __shared__ float As[32][65], Bs[32][65];
    for (int r = 0; r < 8; ++r) {
        int idx = tid + r * 256;          // 0..2047
        int row = idx / 64, col = idx % 64;
        As[row][col] = proj[(bi * 32 + row) * 512 + aoff + col];
        Bs[row][col] = proj[(bj * 32 + row) * 512 + boff + col];
    }
    __syncthreads();

    float acc[2][2] = {{0.f, 0.f}, {0.f, 0.f}};
#pragma unroll 8
    for (int d = 0; d < 64; ++d) {
        float a0 = As[ty * 2][d], a1 = As[ty * 2 + 1][d];
        float b0 = Bs[tx * 2][d], b1 = Bs[tx * 2 + 1][d];
        acc[0][0] += a0 * b0; acc[0][1] += a0 * b1;
        acc[1][0] += a1 * b0; acc[1][1] += a1 * b1;
    }
#pragma unroll
    for (int a = 0; a < 2; ++a) {
        int row = bi * 32 + ty * 2 + a;
        int col = bj * 32 + tx * 2;
        float v0 = expf(acc[a][0] * 0.125f);
        float v1 = expf(acc[a][1] * 0.125f);
        if (m == 0) {
            R[row * NN + col] = v0; R[row * NN + col + 1] = v1;
        } else if (m == 1) {
            P[row * NN + col] = v0; P[row * NN + col + 1] = v1;
        } else {
            // bf16 split by truncation: v = hi + lo + O(2^-16 v)
            u32 b0 = __float_as_uint(v0), b1 = __float_as_uint(v1);
            u32 h0 = b0 & 0xFFFF0000u,   h1 = b1 & 0xFFFF0000u;
            float l0 = v0 - __uint_as_float(h0);
            float l1 = v1 - __uint_as_float(h1);
            ushort2 hw, lw;
            hw.x = (u16)(h0 >> 16); hw.y = (u16)(h1 >> 16);
            lw.x = (u16)(__float_as_uint(l0) >> 16);
            lw.y = (u16)(__float_as_uint(l1) >> 16);
            *(ushort2*)(Qhi + row * NN + col) = hw;
            *(ushort2*)(Qlo + row * NN + col) = lw;
        }
    }
}

// ---------------- split helper: 8 fp32 -> bf16 hi/lo frags (truncation) ----------------
__device__ __forceinline__ void split8(float4 a, float4 b, short8& hi, short8& lo) {
    union { short8 s; u32 u[4]; } H, L;
    float va[8] = {a.x, a.y, a.z, a.w, b.x, b.y, b.z, b.w};
#pragma unroll
    for (int e = 0; e < 4; ++e) {
        float x0 = va[2 * e], x1 = va[2 * e + 1];
        u32 h0 = __float_as_uint(x0) & 0xFFFF0000u;
        u32 h1 = __float_as_uint(x1) & 0xFFFF0000u;
        float l0 = x0 - __uint_as_float(h0);
        float l1 = x1 - __uint_as_float(h1);
        H.u[e] = (h0 >> 16) | h1;
        L.u[e] = (__float_as_uint(l0) >> 16) | (__float_as_uint(l1) & 0xFFFF0000u);
    }
    hi = H.s; lo = L.s;
}

#define MFMA(A, B, C) __builtin_amdgcn_mfma_f32_16x16x32_bf16(A, B, C, 0, 0, 0)

// ---------------- kernel 3: main MFMA contraction ----------------
// block = (i, j-half). M=192 rows of j, N=80 (64 d cols + col64=den), K=384.
// A = Q[j][k] (bf16 hi/lo, global->VGPR direct, L2-resident).
// B[k][n] = P[i,k]*v2[k,n] built in-register per lane (fp32 -> split bf16).
// acc[mf][nf]: wave w owns j rows j0..j0+47 (3 m-frags), all 5 n-frags.
__global__ __launch_bounds__(256, 3) void main_mfma(
    const u16* __restrict__ Qhi, const u16* __restrict__ Qlo,
    const float* __restrict__ R, const float* __restrict__ P,
    const float* __restrict__ v1t, const float* __restrict__ v2t,
    float* __restrict__ num, float* __restrict__ den) {
    int i  = blockIdx.x >> 1;
    int jh = blockIdx.x & 1;
    int tid = (int)threadIdx.x;
    int w = tid >> 6, l = tid & 63;
    int lr = l & 15, lc = l >> 4;          // lr: row/col in frag, lc: k-chunk
    int j0 = jh * 192 + w * 48;

    f32x4 acc[3][5];
#pragma unroll
    for (int mf = 0; mf < 3; ++mf)
#pragma unroll
        for (int nf = 0; nf < 5; ++nf)
            acc[mf][nf] = (f32x4){0.f, 0.f, 0.f, 0.f};

    const float* Pi = P + i * NN;

    for (int k0 = 0; k0 < NN; k0 += 32) {
        int k8 = k0 + lc * 8;
        short8 ahi[3], alo[3];
#pragma unroll
        for (int mf = 0; mf < 3; ++mf) {
            int j = j0 + mf * 16 + lr;
            ahi[mf] = *(const short8*)(Qhi + j * NN + k8);
            alo[mf] = *(const short8*)(Qlo + j * NN + k8);
        }
        float4 pa = *(const float4*)(Pi + k8);
        float4 pb = *(const float4*)(Pi + k8 + 4);
#pragma unroll
        for (int nf = 0; nf < 5; ++nf) {
            float4 ca, cb;
            if (nf < 4) {
                const float* vp = v2t + (nf * 16 + lr) * NN + k8;
                float4 va = *(const float4*)(vp);
                float4 vb = *(const float4*)(vp + 4);
                ca.x = pa.x * va.x; ca.y = pa.y * va.y;
                ca.z = pa.z * va.z; ca.w = pa.w * va.w;
                cb.x = pb.x * vb.x; cb.y = pb.y * vb.y;
                cb.z = pb.z * vb.z; cb.w = pb.w * vb.w;
            } else {
                bool on = (lr == 0);       // col 64 = den column (v2 == 1)
                ca = on ? pa : make_float4(0.f, 0.f, 0.f, 0.f);
                cb = on ? pb : make_float4(0.f, 0.f, 0.f, 0.f);
            }
            short8 bhi, blo;
            split8(ca, cb, bhi, blo);
#pragma unroll
            for (int mf = 0; mf < 3; ++mf) {
                acc[mf][nf] = MFMA(ahi[mf], bhi, acc[mf][nf]);
                acc[mf][nf] = MFMA(ahi[mf], blo, acc[mf][nf]);
                acc[mf][nf] = MFMA(alo[mf], bhi, acc[mf][nf]);
            }
        }
    }

    // epilogue: num[i,d] += sum_j R[i,j]*v1[j,d]*T[j,d]; den via col 64.
    // acc[mf][nf] reg r  <->  j = j0+mf*16+lc*4+r, col = nf*16+lr.
    float4 rj[3];
#pragma unroll
    for (int mf = 0; mf < 3; ++mf)
        rj[mf] = *(const float4*)(R + i * NN + j0 + mf * 16 + lc * 4);

    __shared__ float sh[4][80];
#pragma unroll
    for (int nf = 0; nf < 5; ++nf) {
        float s = 0.f;
#pragma unroll
        for (int mf = 0; mf < 3; ++mf) {
            f32x4 a = acc[mf][nf];
            if (nf < 4) {
                const float* vp = v1t + (nf * 16 + lr) * NN + j0 + mf * 16 + lc * 4;
                float4 v1v = *(const float4*)(vp);
                s += a[0] * rj[mf].x * v1v.x + a[1] * rj[mf].y * v1v.y
                   + a[2] * rj[mf].z * v1v.z + a[3] * rj[mf].w * v1v.w;
            } else {
                s += a[0] * rj[mf].x + a[1] * rj[mf].y
                   + a[2] * rj[mf].z + a[3] * rj[mf].w;
            }
        }
        s += __shfl_xor(s, 16, 64);
        s += __shfl_xor(s, 32, 64);
        if (l < 16) sh[w][nf * 16 + l] = s;
    }
    __syncthreads();
    if (tid < 80) {
        float v = sh[0][tid] + sh[1][tid] + sh[2][tid] + sh[3][tid];
        if (tid < 64)       atomicAdd(&num[i * 64 + tid], v);
        else if (tid == 64) atomicAdd(&den[i], v);
    }
}

// ---------------- kernel 4: out = num / den ----------------
__global__ void finalize_kernel(const float* __restrict__ num, const float* __restrict__ den,
                                float* __restrict__ out) {
    int idx = blockIdx.x * 256 + threadIdx.x;   // 24576
    out[idx] = num[idx] / den[idx >> 6];
}

extern "C" void kernel_launch(void* const* d_in, const int* in_sizes, int n_in,
                              void* d_out, int out_size, void* d_ws, size_t ws_size,
                              hipStream_t stream) {
    const float* x = (const float*)d_in[0];      // [1,384,64]
    const float* W = (const float*)d_in[1];      // [512,64]
    float* out = (float*)d_out;                  // [384,64]

    float* ws   = (float*)d_ws;                  // ~2.86 MB used
    float* proj = ws;                            // 196608
    float* R    = ws + 196608;                   // 147456
    float* P    = ws + 344064;                   // 147456
    float* v1t  = ws + 491520;                   // 24576  [64][384]
    float* v2t  = ws + 516096;                   // 24576  [64][384]
    float* num  = ws + 540672;                   // 24576
    float* den  = ws + 565248;                   // 384
    u16*   Qhi  = (u16*)(ws + 565632);           // 147456 u16
    u16*   Qlo  = (u16*)(ws + 639360);           // 147456 u16

    hipMemsetAsync(num, 0, 24960 * sizeof(float), stream);  // num + den

    proj_kernel<<<NN, 256, 0, stream>>>(x, W, proj, v1t, v2t);
    scores_exp_kernel<<<dim3(12, 12, 3), 256, 0, stream>>>(proj, R, P, Qhi, Qlo);
    main_mfma<<<768, 256, 0, stream>>>(Qhi, Qlo, R, P, v1t, v2t, num, den);
    finalize_kernel<<<96, 256, 0, stream>>>(num, den, out);
}

// Round 3
// 105.866 us; speedup vs baseline: 1.6937x; 1.2962x over previous
//
#include <hip/hip_runtime.h>
#include <math.h>

// TripleAttention: B=1, N=384, C=D=64, H=1.
// out[i,d] = num/den,
//   num[i,d] = sum_{j,k} R[i,j] P[i,k] Q[j,k] v1[j,d] v2[k,d]
//   den[i]   = sum_{j,k} R[i,j] P[i,k] Q[j,k]
// R=exp(AB), P=exp(CD), Q=exp(EF); reference's global-max shift cancels in the
// ratio. Main contraction: bf16 MFMA, hi/lo split (3 products) ~2^-16 accuracy.
// B-tile (P (x) v2 + den column) built cooperatively in LDS, double-buffered.

#define NN 384

using short8 = __attribute__((ext_vector_type(8))) short;
using f32x4  = __attribute__((ext_vector_type(4))) float;
typedef unsigned short u16;
typedef unsigned int u32;

// ---------------- kernel 1: proj = x @ W^T  [384,512]; also v1t/v2t ----------------
__global__ void proj_kernel(const float* __restrict__ x, const float* __restrict__ W,
                            float* __restrict__ proj, float* __restrict__ v1t,
                            float* __restrict__ v2t) {
    int n = blockIdx.x;
    __shared__ float xs[64];
    if (threadIdx.x < 64) xs[threadIdx.x] = x[n * 64 + threadIdx.x];
    __syncthreads();
    const float4* xv4 = (const float4*)xs;
    for (int r = 0; r < 2; ++r) {
        int o = threadIdx.x + r * 256;
        const float4* w4 = (const float4*)(W + o * 64);
        float s = 0.f;
#pragma unroll
        for (int c = 0; c < 16; ++c) {
            float4 wv = w4[c];
            float4 xv = xv4[c];
            s += wv.x * xv.x + wv.y * xv.y + wv.z * xv.z + wv.w * xv.w;
        }
        proj[n * 512 + o] = s;
        if (o >= 448)      v2t[(o - 448) * NN + n] = s;   // v2^T [d][k]
        else if (o >= 384) v1t[(o - 384) * NN + n] = s;   // v1^T [d][j]
    }
}

// ---------------- kernel 2: scores + exp (+ bf16 split for Q) ----------------
// m=0: R[i,j]=exp(a.b/8); m=1: P[i,k]=exp(c.d/8); m=2: Q[j,k]=exp(e.f/8)->Qhi/Qlo
__global__ void scores_exp_kernel(const float* __restrict__ proj,
                                  float* __restrict__ R, float* __restrict__ P,
                                  u16* __restrict__ Qhi, u16* __restrict__ Qlo) {
    int m = blockIdx.z;
    int bi = blockIdx.y, bj = blockIdx.x;
    int tid = threadIdx.x;
    int tx = tid % 16, ty = tid / 16;
    int aoff, boff;
    if (m == 0)      { aoff = 0;   boff = 64;  }
    else if (m == 1) { aoff = 128; boff = 192; }
    else             { aoff = 256; boff = 320; }

    __shared__ float As[32][65], Bs[32][65];
    for (int r = 0; r < 8; ++r) {
        int idx = tid + r * 256;          // 0..2047
        int row = idx / 64, col = idx % 64;
        As[row][col] = proj[(bi * 32 + row) * 512 + aoff + col];
        Bs[row][col] = proj[(bj * 32 + row) * 512 + boff + col];
    }
    __syncthreads();

    float acc[2][2] = {{0.f, 0.f}, {0.f, 0.f}};
#pragma unroll 8
    for (int d = 0; d < 64; ++d) {
        float a0 = As[ty * 2][d], a1 = As[ty * 2 + 1][d];
        float b0 = Bs[tx * 2][d], b1 = Bs[tx * 2 + 1][d];
        acc[0][0] += a0 * b0; acc[0][1] += a0 * b1;
        acc[1][0] += a1 * b0; acc[1][1] += a1 * b1;
    }
#pragma unroll
    for (int a = 0; a < 2; ++a) {
        int row = bi * 32 + ty * 2 + a;
        int col = bj * 32 + tx * 2;
        float v0 = expf(acc[a][0] * 0.125f);
        float v1 = expf(acc[a][1] * 0.125f);
        if (m == 0) {
            R[row * NN + col] = v0; R[row * NN + col + 1] = v1;
        } else if (m == 1) {
            P[row * NN + col] = v0; P[row * NN + col + 1] = v1;
        } else {
            u32 b0 = __float_as_uint(v0), b1 = __float_as_uint(v1);
            u32 h0 = b0 & 0xFFFF0000u,   h1 = b1 & 0xFFFF0000u;
            float l0 = v0 - __uint_as_float(h0);
            float l1 = v1 - __uint_as_float(h1);
            ushort2 hw, lw;
            hw.x = (u16)(h0 >> 16); hw.y = (u16)(h1 >> 16);
            lw.x = (u16)(__float_as_uint(l0) >> 16);
            lw.y = (u16)(__float_as_uint(l1) >> 16);
            *(ushort2*)(Qhi + row * NN + col) = hw;
            *(ushort2*)(Qlo + row * NN + col) = lw;
        }
    }
}

#define MFMA(A, B, C) __builtin_amdgcn_mfma_f32_16x16x32_bf16(A, B, C, 0, 0, 0)

// ---------------- kernel 3: main MFMA contraction ----------------
// block = (i, jh): M=192 (j), N=80 (64 d + den col 64 + 15 zero), K=384.
// A = Q[j][k] bf16 hi/lo straight from L2. B[k][n] = P[i,k]*v2[k,n] built
// cooperatively into double-buffered LDS ([80 n][40 k] padded, hi/lo).
__global__ __launch_bounds__(256, 3) void main_mfma(
    const u16* __restrict__ Qhi, const u16* __restrict__ Qlo,
    const float* __restrict__ R, const float* __restrict__ P,
    const float* __restrict__ v1t, const float* __restrict__ v2t,
    float* __restrict__ num0, float* __restrict__ num1,
    float* __restrict__ den0, float* __restrict__ den1) {
    int i  = blockIdx.x >> 1;
    int jh = blockIdx.x & 1;
    int tid = (int)threadIdx.x;
    int w = tid >> 6, l = tid & 63;
    int lr = l & 15, lc = l >> 4;
    int j0 = jh * 192 + w * 48;

    __shared__ float p_s[NN];
    __shared__ u16 Bh[2][80 * 40];
    __shared__ u16 Bl[2][80 * 40];
    __shared__ float sh[4][80];

    p_s[tid] = P[i * NN + tid];
    if (tid < 128) p_s[256 + tid] = P[i * NN + 256 + tid];

    f32x4 acc[3][5];
#pragma unroll
    for (int mf = 0; mf < 3; ++mf)
#pragma unroll
        for (int nf = 0; nf < 5; ++nf)
            acc[mf][nf] = (f32x4){0.f, 0.f, 0.f, 0.f};

    __syncthreads();   // p_s ready

    // cooperative B-build for k-step starting at k0 into buffer buf
    auto BUILD = [&](int buf, int k0) {
        {
            int n = tid >> 2, kk = (tid & 3) * 8;
            const float* vp = v2t + n * NN + k0 + kk;
            float4 va = *(const float4*)vp;
            float4 vb = *(const float4*)(vp + 4);
            float pr[8] = {va.x * p_s[k0 + kk + 0], va.y * p_s[k0 + kk + 1],
                           va.z * p_s[k0 + kk + 2], va.w * p_s[k0 + kk + 3],
                           vb.x * p_s[k0 + kk + 4], vb.y * p_s[k0 + kk + 5],
                           vb.z * p_s[k0 + kk + 6], vb.w * p_s[k0 + kk + 7]};
            u32* dh = (u32*)&Bh[buf][n * 40 + kk];
            u32* dl = (u32*)&Bl[buf][n * 40 + kk];
#pragma unroll
            for (int e = 0; e < 4; ++e) {
                float x0 = pr[2 * e], x1 = pr[2 * e + 1];
                u32 h0 = __float_as_uint(x0) & 0xFFFF0000u;
                u32 h1 = __float_as_uint(x1) & 0xFFFF0000u;
                float l0 = x0 - __uint_as_float(h0);
                float l1 = x1 - __uint_as_float(h1);
                dh[e] = (h0 >> 16) | h1;
                dl[e] = (__float_as_uint(l0) >> 16) |
                        (__float_as_uint(l1) & 0xFFFF0000u);
            }
        }
        if (tid < 64) {   // den block: col 64 = P, cols 65..79 = 0
            int n = 64 + (tid >> 2), kk = (tid & 3) * 8;
            u32* dh = (u32*)&Bh[buf][n * 40 + kk];
            u32* dl = (u32*)&Bl[buf][n * 40 + kk];
            if (n == 64) {
#pragma unroll
                for (int e = 0; e < 4; ++e) {
                    float x0 = p_s[k0 + kk + 2 * e], x1 = p_s[k0 + kk + 2 * e + 1];
                    u32 h0 = __float_as_uint(x0) & 0xFFFF0000u;
                    u32 h1 = __float_as_uint(x1) & 0xFFFF0000u;
                    float l0 = x0 - __uint_as_float(h0);
                    float l1 = x1 - __uint_as_float(h1);
                    dh[e] = (h0 >> 16) | h1;
                    dl[e] = (__float_as_uint(l0) >> 16) |
                            (__float_as_uint(l1) & 0xFFFF0000u);
                }
            } else {
#pragma unroll
                for (int e = 0; e < 4; ++e) { dh[e] = 0u; dl[e] = 0u; }
            }
        }
    };

    BUILD(0, 0);
    __syncthreads();

    for (int t = 0; t < 12; ++t) {
        int b = t & 1;
        int k8 = t * 32 + lc * 8;
        short8 ahi[3], alo[3];
#pragma unroll
        for (int mf = 0; mf < 3; ++mf) {
            int j = j0 + mf * 16 + lr;
            ahi[mf] = *(const short8*)(Qhi + j * NN + k8);
            alo[mf] = *(const short8*)(Qlo + j * NN + k8);
        }
        if (t < 11) BUILD(b ^ 1, (t + 1) * 32);
#pragma unroll
        for (int nf = 0; nf < 5; ++nf) {
            short8 bh = *(const short8*)&Bh[b][(nf * 16 + lr) * 40 + lc * 8];
            short8 bl = *(const short8*)&Bl[b][(nf * 16 + lr) * 40 + lc * 8];
#pragma unroll
            for (int mf = 0; mf < 3; ++mf) {
                acc[mf][nf] = MFMA(ahi[mf], bh, acc[mf][nf]);
                acc[mf][nf] = MFMA(ahi[mf], bl, acc[mf][nf]);
                acc[mf][nf] = MFMA(alo[mf], bh, acc[mf][nf]);
            }
        }
        __syncthreads();
    }

    // epilogue: s[n] = sum over this wave's 48 j of R*v1*T ; den via col 64.
    // acc[mf][nf] reg r <-> j = j0+mf*16+lc*4+r, col = nf*16+lr.
    float4 rj[3];
#pragma unroll
    for (int mf = 0; mf < 3; ++mf)
        rj[mf] = *(const float4*)(R + i * NN + j0 + mf * 16 + lc * 4);

#pragma unroll
    for (int nf = 0; nf < 5; ++nf) {
        float s = 0.f;
#pragma unroll
        for (int mf = 0; mf < 3; ++mf) {
            f32x4 a = acc[mf][nf];
            if (nf < 4) {
                const float* vp = v1t + (nf * 16 + lr) * NN + j0 + mf * 16 + lc * 4;
                float4 v1v = *(const float4*)vp;
                s += a[0] * rj[mf].x * v1v.x + a[1] * rj[mf].y * v1v.y
                   + a[2] * rj[mf].z * v1v.z + a[3] * rj[mf].w * v1v.w;
            } else {
                s += a[0] * rj[mf].x + a[1] * rj[mf].y
                   + a[2] * rj[mf].z + a[3] * rj[mf].w;
            }
        }
        s += __shfl_xor(s, 16, 64);
        s += __shfl_xor(s, 32, 64);
        if (l < 16) sh[w][nf * 16 + l] = s;
    }
    __syncthreads();
    if (tid < 80) {
        float v = sh[0][tid] + sh[1][tid] + sh[2][tid] + sh[3][tid];
        if (tid < 64) (jh ? num1 : num0)[i * 64 + tid] = v;
        else if (tid == 64) (jh ? den1 : den0)[i] = v;
    }
}

// ---------------- kernel 4: out = (num0+num1)/(den0+den1) ----------------
__global__ void finalize_kernel(const float* __restrict__ num0, const float* __restrict__ num1,
                                const float* __restrict__ den0, const float* __restrict__ den1,
                                float* __restrict__ out) {
    int idx = blockIdx.x * 256 + threadIdx.x;   // 24576
    int i = idx >> 6;
    out[idx] = (num0[idx] + num1[idx]) / (den0[i] + den1[i]);
}

extern "C" void kernel_launch(void* const* d_in, const int* in_sizes, int n_in,
                              void* d_out, int out_size, void* d_ws, size_t ws_size,
                              hipStream_t stream) {
    const float* x = (const float*)d_in[0];      // [1,384,64]
    const float* W = (const float*)d_in[1];      // [512,64]
    float* out = (float*)d_out;                  // [384,64]

    float* ws   = (float*)d_ws;                  // 2.75 MB used
    float* R    = ws;                            // 147456
    float* P    = ws + 147456;                   // 147456
    float* v1t  = ws + 294912;                   // 24576  [64][384]
    float* v2t  = ws + 319488;                   // 24576  [64][384]
    u16*   Qhi  = (u16*)(ws + 344064);           // 147456 u16
    u16*   Qlo  = (u16*)(ws + 417792);           // 147456 u16
    float* proj = ws + 491520;                   // 196608
    // num/den partials alias proj (proj dead after scores_exp; num written later)
    float* num0 = proj;                          // 24576
    float* num1 = proj + 24576;                  // 24576
    float* den0 = proj + 49152;                  // 384
    float* den1 = proj + 49536;                  // 384

    proj_kernel<<<NN, 256, 0, stream>>>(x, W, proj, v1t, v2t);
    scores_exp_kernel<<<dim3(12, 12, 3), 256, 0, stream>>>(proj, R, P, Qhi, Qlo);
    main_mfma<<<768, 256, 0, stream>>>(Qhi, Qlo, R, P, v1t, v2t,
                                       num0, num1, den0, den1);
    finalize_kernel<<<96, 256, 0, stream>>>(num0, num1, den0, den1, out);
}